// Round 5
// baseline (204.414 us; speedup 1.0000x reference)
//
#include <hip/hip_runtime.h>
#include <math.h>

typedef __bf16 bf16x8 __attribute__((ext_vector_type(8)));
typedef float f32x4 __attribute__((ext_vector_type(4)));

// ---------- helpers ----------

__device__ __forceinline__ unsigned short f2bf(float f) {
    unsigned int u = __float_as_uint(f);
    u += 0x7FFFu + ((u >> 16) & 1u);   // round-to-nearest-even
    return (unsigned short)(u >> 16);
}

// fast logcosh via HW v_exp/v_log (TRANS pipe). abs err ~1e-6/elem, budget 0.02.
__device__ __forceinline__ float logcosh_fast(float v) {
    float a = fabsf(v);
    float t = __expf(-2.0f * a);
    return a + (__logf(1.0f + t) - 0.6931471805599453f);
}

// DPP row_shr add; after shr 1,2,4,8 lane 15 of each 16-lane row holds row sum.
template <int CTRL>
__device__ __forceinline__ float dppadd(float x) {
    int y = __builtin_amdgcn_update_dpp(0, __float_as_int(x), CTRL, 0xf, 0xf, true);
    return x + __int_as_float(y);
}

__device__ __forceinline__ void gload_lds16(const void* g, void* l) {
    __builtin_amdgcn_global_load_lds(
        (__attribute__((address_space(1))) void*)(void*)g,
        (__attribute__((address_space(3))) void*)l, 16, 0, 0);
}

#define SBAR()  __builtin_amdgcn_s_barrier()
#define SCHED() __builtin_amdgcn_sched_barrier(0)

// ---------- kernel 1: invert permutations ----------
__global__ __launch_bounds__(256) void k_invert(const int* __restrict__ perms,
                                                int* __restrict__ inv) {
    int t = blockIdx.x * 256 + threadIdx.x;
    int g = t >> 10, n = t & 1023;
    inv[(g << 10) + perms[t]] = n;
}

// ---------- kernel 2: bT[j][k] = bf16(W[inv[g][k]][f]), j = g*16+f ----------
__global__ __launch_bounds__(256) void k_build_bt(const float* __restrict__ W,
                                                  const int* __restrict__ inv,
                                                  unsigned short* __restrict__ bT) {
    int j = blockIdx.x;
    int g = j >> 4, f = j & 15;
    const int* invg = inv + (g << 10);
    size_t rowbase = (size_t)j << 10;
#pragma unroll
    for (int i = 0; i < 4; ++i) {
        int k = (i << 8) + threadIdx.x;
        int n = invg[k];
        bT[rowbase + k] = f2bf(W[(n << 4) + f]);
    }
}

// ---------- kernel 3: x -> bf16, out[row] = v_bias * sum(x[row]) ----------
__global__ __launch_bounds__(256) void k_convert(const float* __restrict__ x,
                                                 const float* __restrict__ vb,
                                                 unsigned short* __restrict__ xb,
                                                 float* __restrict__ out) {
    int row = blockIdx.x, tid = threadIdx.x;
    size_t base = ((size_t)row << 10) + (tid << 2);
    float4 v = *reinterpret_cast<const float4*>(x + base);
    ushort4 h;
    h.x = f2bf(v.x); h.y = f2bf(v.y); h.z = f2bf(v.z); h.w = f2bf(v.w);
    *reinterpret_cast<ushort4*>(xb + base) = h;
    float s = v.x + v.y + v.z + v.w;
#pragma unroll
    for (int off = 32; off > 0; off >>= 1) s += __shfl_down(s, off);
    __shared__ float ls[4];
    if ((tid & 63) == 0) ls[tid >> 6] = s;
    __syncthreads();
    if (tid == 0) out[row] = vb[0] * (ls[0] + ls[1] + ls[2] + ls[3]);
}

// ---------- kernel 4: 256x256 GEMM, m201-style 8-phase schedule + fused logcosh ----
// 16 K-tiles BK=64, dbuf LDS, 8 fine phases per 2 K-tiles:
//   phase = {small ds-read group + 1 half-tile stage; s_barrier; counted lgkm;
//            setprio(1) 16 MFMA setprio(0); s_barrier}
// vmcnt(2) only at phases 4/8. Raw s_barrier (no implicit vmcnt drain).
// Stage slots: ph1-3=(t+1:Ah1,Bh0,Bh1) ph4-7=(t+2:Ah0,Ah1,Bh0,Bh1) ph8=(t+3:Ah0).

#define MFMA_QUAD(MH, NH)                                                        \
    _Pragma("unroll") for (int m_ = 0; m_ < 4; ++m_)                             \
    _Pragma("unroll") for (int n_ = 0; n_ < 2; ++n_)                             \
    _Pragma("unroll") for (int kk_ = 0; kk_ < 2; ++kk_)                          \
        acc[(MH) * 4 + m_][(NH) * 2 + n_] =                                      \
            __builtin_amdgcn_mfma_f32_16x16x32_bf16(                             \
                aF[(MH) * 4 + m_][kk_], bF[(NH) * 2 + n_][kk_],                  \
                acc[(MH) * 4 + m_][(NH) * 2 + n_], 0, 0, 0);

__global__ __launch_bounds__(512) void k_gemm(const unsigned short* __restrict__ xb,
                                              const unsigned short* __restrict__ bT,
                                              const float* __restrict__ bias,
                                              float* __restrict__ partial, int B) {
    __shared__ unsigned short As[2][256 * 64];
    __shared__ unsigned short Bs[2][256 * 64];

    const int tid = threadIdx.x;
    const int lane = tid & 63;
    const int wv = tid >> 6;           // 0..7
    const int wm = wv >> 2;            // 0..1  (M half)
    const int wn = wv & 3;             // 0..3  (N quarter)
    const int lr = lane & 15;
    const int lk = lane >> 4;

    // XCD-bijective swizzle (nwg = 1024, % 8 == 0)
    const int fid = blockIdx.y * gridDim.x + blockIdx.x;
    const int cpx = (gridDim.x * gridDim.y) >> 3;
    const int swz = (fid & 7) * cpx + (fid >> 3);
    const int cbx = swz & 15;          // col block (0..15)
    const int row0 = (swz >> 4) << 8;  // row block * 256
    const int j0 = cbx << 8;

    const unsigned short* xbase = xb + ((size_t)row0 << 10);
    const unsigned short* bbase = bT + ((size_t)j0 << 10);

    // hoisted per-wave LDS read bases (short units); reads use +m*1024 imm offsets
    const int aRow = (wm * 128 + lr) * 64;
    const int bRow = (wn * 64 + lr) * 64;
    const int po0 = (lk ^ (lr & 7)) * 8;
    const int po1 = ((4 + lk) ^ (lr & 7)) * 8;

    // stage one half-tile (128 rows x 64 cols bf16 = 16KB) = 2 gload_lds x 512 thr
    auto stage_half = [&](unsigned short* dst, const unsigned short* src, int h) {
#pragma unroll
        for (int j = 0; j < 2; ++j) {
            int c0 = (h * 128 + j * 64) * 8;       // base chunk of this instr
            int cc = c0 + tid;                     // this thread's 16B chunk
            int r = cc >> 3;                       // tile row 0..255
            int cs = (cc & 7) ^ (r & 7);           // pre-swizzled source octet
            gload_lds16(src + (((size_t)r) << 10) + (cs << 3),
                        dst + ((c0 + wv * 64) << 3));
        }
    };
    // part: 0=A h0, 1=A h1, 2=B h0, 3=B h1 (compile-time); tile runtime
    auto stage_slot = [&](int tile, int part) {
        if (tile > 15) return;
        int p = tile & 1;
        const unsigned short* src = (part < 2 ? xbase : bbase) + (tile << 6);
        unsigned short* dst = (part < 2 ? &As[p][0] : &Bs[p][0]);
        stage_half(dst, src, part & 1);
    };

    f32x4 acc[8][4];
#pragma unroll
    for (int m = 0; m < 8; ++m)
#pragma unroll
        for (int n = 0; n < 4; ++n)
            acc[m][n] = {0.f, 0.f, 0.f, 0.f};

    // ---- prologue: tile0 all 4 halves + (tile1, A h0); drain tile0 ----
    stage_slot(0, 0); stage_slot(0, 1); stage_slot(0, 2); stage_slot(0, 3);
    stage_slot(1, 0);
    asm volatile("s_waitcnt vmcnt(2)" ::: "memory");   // tile0 landed
    SCHED();
    SBAR();

    // ---- main loop: 8 iterations x 2 K-tiles x 4 phases ----
    for (int tt = 0; tt < 8; ++tt) {
        const int t = tt * 2;

        // one K-tile = 4 phases; st1 = tile for ph1-3 slots, st4 = tile for ph4 slot
        auto half_iter = [&](const unsigned short* Ap, const unsigned short* Bp,
                             int st1, int st4, int vm) {
            bf16x8 aF[8][2], bF[4][2];

            // ---- phase 1: 12 reads (q00 frags) + stage(st1, Ah1)
#pragma unroll
            for (int m = 0; m < 4; ++m) {
                aF[m][0] = *reinterpret_cast<const bf16x8*>(Ap + aRow + po0 + m * 1024);
                aF[m][1] = *reinterpret_cast<const bf16x8*>(Ap + aRow + po1 + m * 1024);
            }
#pragma unroll
            for (int n = 0; n < 2; ++n) {
                bF[n][0] = *reinterpret_cast<const bf16x8*>(Bp + bRow + po0 + n * 1024);
                bF[n][1] = *reinterpret_cast<const bf16x8*>(Bp + bRow + po1 + n * 1024);
            }
            stage_slot(st1, 1);
            SCHED();
            SBAR();
            asm volatile("s_waitcnt lgkmcnt(0)" ::: "memory");
            SCHED();
            __builtin_amdgcn_s_setprio(1);
            MFMA_QUAD(0, 0)
            __builtin_amdgcn_s_setprio(0);
            SCHED();
            SBAR();

            // ---- phase 2: 8 reads (aF4-7) then 4 reads (bF2-3), stage(st1, Bh0)
#pragma unroll
            for (int m = 4; m < 8; ++m) {
                aF[m][0] = *reinterpret_cast<const bf16x8*>(Ap + aRow + po0 + m * 1024);
                aF[m][1] = *reinterpret_cast<const bf16x8*>(Ap + aRow + po1 + m * 1024);
            }
            SCHED();   // pin issue order: aF4-7 before bF2-3 (lgkm(4) ledger)
#pragma unroll
            for (int n = 2; n < 4; ++n) {
                bF[n][0] = *reinterpret_cast<const bf16x8*>(Bp + bRow + po0 + n * 1024);
                bF[n][1] = *reinterpret_cast<const bf16x8*>(Bp + bRow + po1 + n * 1024);
            }
            stage_slot(st1, 2);
            SCHED();
            SBAR();
            asm volatile("s_waitcnt lgkmcnt(4)" ::: "memory");   // aF4-7 ready
            SCHED();
            __builtin_amdgcn_s_setprio(1);
            MFMA_QUAD(1, 0)
            __builtin_amdgcn_s_setprio(0);
            SCHED();
            SBAR();

            // ---- phase 3: no reads; stage(st1, Bh1)
            stage_slot(st1, 3);
            SCHED();
            SBAR();
            asm volatile("s_waitcnt lgkmcnt(0)" ::: "memory");   // bF2-3 ready
            SCHED();
            __builtin_amdgcn_s_setprio(1);
            MFMA_QUAD(0, 1)
            __builtin_amdgcn_s_setprio(0);
            SCHED();
            SBAR();   // all waves' reads of this buffer drained

            // ---- phase 4: stage(st4, Ah0) now safe; MFMA q11; counted vmcnt
            stage_slot(st4, 0);
            SCHED();
            SBAR();
            __builtin_amdgcn_s_setprio(1);
            MFMA_QUAD(1, 1)
            __builtin_amdgcn_s_setprio(0);
            SCHED();
            if (vm == 2)      { asm volatile("s_waitcnt vmcnt(2)" ::: "memory"); }
            else if (vm == 0) { asm volatile("s_waitcnt vmcnt(0)" ::: "memory"); }
            SCHED();
            SBAR();
        };

        half_iter(As[0], Bs[0], t + 1, t + 2, (tt < 7) ? 2 : 0);
        half_iter(As[1], Bs[1], t + 2, t + 3, (tt < 7) ? 2 : -1);
    }

    // ---- epilogue: fast logcosh + DPP row-reduce; reuse As as scratch ----
    float* rowsum = (float*)&As[0][0];   // [4][256]
    const float bv = bias[lr];           // C col % 16 == lane&15
#pragma unroll
    for (int m = 0; m < 8; ++m) {
#pragma unroll
        for (int r = 0; r < 4; ++r) {
            float s = 0.f;
#pragma unroll
            for (int n = 0; n < 4; ++n) s += logcosh_fast(acc[m][n][r] + bv);
            s = dppadd<0x111>(s);
            s = dppadd<0x112>(s);
            s = dppadd<0x114>(s);
            s = dppadd<0x118>(s);
            if (lr == 15)
                rowsum[wn * 256 + wm * 128 + m * 16 + lk * 4 + r] = s;
        }
    }
    __syncthreads();
    if (tid < 256) {
        float s = rowsum[tid] + rowsum[256 + tid] + rowsum[512 + tid] + rowsum[768 + tid];
        partial[(size_t)cbx * B + row0 + tid] = s;
    }
}

// ---------- kernel 5: out[b] += sum_cb partial[cb][b] ----------
__global__ __launch_bounds__(256) void k_final(const float* __restrict__ partial,
                                               float* __restrict__ out, int ncb, int B) {
    int b = blockIdx.x * 256 + threadIdx.x;
    float s = out[b];
    for (int c = 0; c < ncb; ++c) s += partial[(size_t)c * B + b];
    out[b] = s;
}

// ---------- launch ----------
extern "C" void kernel_launch(void* const* d_in, const int* in_sizes, int n_in,
                              void* d_out, int out_size, void* d_ws, size_t ws_size,
                              hipStream_t stream) {
    const float* x      = (const float*)d_in[0];  // [B,1024]
    const float* W      = (const float*)d_in[1];  // [1024,16]
    const float* bias   = (const float*)d_in[2];  // [16]
    const float* v_bias = (const float*)d_in[3];  // [1]
    const int*   perms  = (const int*)d_in[4];    // [G,1024]
    float* out = (float*)d_out;

    const int N  = 1024;
    const int B  = in_sizes[0] / N;   // 16384
    const int G  = in_sizes[4] / N;   // 256
    const int GF = G * 16;            // 4096
    const int NCB = GF / 256;         // 16 col blocks

    char* w = (char*)d_ws;
    unsigned short* xb = (unsigned short*)w;                           // B*N*2   = 32 MB
    unsigned short* bT = (unsigned short*)(w + (size_t)B * N * 2);     // GF*N*2  = 8 MB
    int* inv = (int*)(w + (size_t)B * N * 2 + (size_t)GF * N * 2);     // G*N*4   = 1 MB
    float* partial = (float*)(w + (size_t)B * N * 2 + (size_t)GF * N * 2
                              + (size_t)G * N * 4);                    // NCB*B*4 = 1 MB

    k_invert<<<G * N / 256, 256, 0, stream>>>(perms, inv);
    k_build_bt<<<GF, 256, 0, stream>>>(W, inv, bT);
    k_convert<<<B, 256, 0, stream>>>(x, v_bias, xb, out);
    k_gemm<<<dim3(NCB, B / 256), 512, 0, stream>>>(xb, bT, bias, partial, B);
    k_final<<<B / 256, 256, 0, stream>>>(partial, out, NCB, B);
}